// Round 6
// baseline (674.011 us; speedup 1.0000x reference)
//
#include <hip/hip_runtime.h>

#define N_NODES 100000
#define N_EDGES 1600000
#define HID 128
#define LAT 64
#define N_LAYERS 3
#define N_GRAPHS 1000
#define NB_SCAN ((N_NODES + 255) / 256)  // 391

typedef short bf16x8 __attribute__((ext_vector_type(8)));
typedef float f32x4 __attribute__((ext_vector_type(4)));

__device__ __forceinline__ float bf2f(unsigned short h) {
    union { unsigned int u; float f; } c;
    c.u = ((unsigned int)h) << 16;
    return c.f;
}
__device__ __forceinline__ unsigned short f2bf(float f) {
    union { float f; unsigned int u; } c;
    c.f = f;
    unsigned int u = c.u;
    return (unsigned short)((u + 0x7fffu + ((u >> 16) & 1u)) >> 16);
}
__device__ __forceinline__ unsigned int pack2(float a, float b) {
    return (unsigned int)f2bf(a) | ((unsigned int)f2bf(b) << 16);
}
__device__ __forceinline__ void addrow(float* acc, uint4 w) {
    acc[0] += bf2f((unsigned short)w.x); acc[1] += bf2f((unsigned short)(w.x >> 16));
    acc[2] += bf2f((unsigned short)w.y); acc[3] += bf2f((unsigned short)(w.y >> 16));
    acc[4] += bf2f((unsigned short)w.z); acc[5] += bf2f((unsigned short)(w.z >> 16));
    acc[6] += bf2f((unsigned short)w.w); acc[7] += bf2f((unsigned short)(w.w >> 16));
}

// ---------------- convert x fp32 -> bf16 ----------------
__global__ __launch_bounds__(256) void cvt_x_kernel(const float* __restrict__ x,
                                                    unsigned short* __restrict__ xb, int n4) {
    int i = blockIdx.x * 256 + threadIdx.x;
    if (i >= n4) return;
    float4 v = ((const float4*)x)[i];
    ((uint2*)xb)[i] = make_uint2(pack2(v.x, v.y), pack2(v.z, v.w));
}

// ---------------- W [k][n] fp32 -> Wt [n][k] bf16, 6 matrices ----------------
__global__ __launch_bounds__(256) void wt_kernel(const float* __restrict__ W1,
                                                 const float* __restrict__ W2,
                                                 unsigned short* __restrict__ Wt) {
    int m = blockIdx.x;  // 0..5 : layer*2 + phase
    const float* W = ((m & 1) ? W2 : W1) + (size_t)(m >> 1) * HID * HID;
    unsigned short* D = Wt + (size_t)m * HID * HID;
    for (int idx = threadIdx.x; idx < HID * HID; idx += 256) {
        int n = idx >> 7, k = idx & 127;
        D[n * HID + k] = f2bf(W[k * HID + n]);
    }
}

// ---------------- CSR build ----------------
__global__ __launch_bounds__(256) void count_kernel(const int* __restrict__ ei,
                                                    int* __restrict__ deg) {
    int e = blockIdx.x * 256 + threadIdx.x;
    if (e < N_EDGES) atomicAdd(&deg[ei[N_EDGES + e]], 1);
}

__global__ __launch_bounds__(256) void scanA_kernel(const int* __restrict__ deg,
                                                    int* __restrict__ bsum) {
    __shared__ int s[256];
    int t = threadIdx.x;
    int n = blockIdx.x * 256 + t;
    s[t] = (n < N_NODES) ? deg[n] : 0;
    __syncthreads();
    for (int d = 128; d > 0; d >>= 1) {
        if (t < d) s[t] += s[t + d];
        __syncthreads();
    }
    if (t == 0) bsum[blockIdx.x] = s[0];
}

__global__ __launch_bounds__(512) void scanB_kernel(const int* __restrict__ bsum,
                                                    int* __restrict__ boff) {
    __shared__ int s[512];
    int t = threadIdx.x;
    s[t] = (t < NB_SCAN) ? bsum[t] : 0;
    __syncthreads();
    for (int d = 1; d < 512; d <<= 1) {
        int v = (t >= d) ? s[t - d] : 0;
        __syncthreads();
        s[t] += v;
        __syncthreads();
    }
    if (t < NB_SCAN) boff[t] = (t == 0) ? 0 : s[t - 1];
}

__global__ __launch_bounds__(256) void scanC_kernel(const int* __restrict__ deg,
                                                    const int* __restrict__ boff,
                                                    int* __restrict__ offs,
                                                    int* __restrict__ cursor) {
    __shared__ int s[256];
    int t = threadIdx.x;
    int n = blockIdx.x * 256 + t;
    int v = (n < N_NODES) ? deg[n] : 0;
    s[t] = v;
    __syncthreads();
    for (int d = 1; d < 256; d <<= 1) {
        int u = (t >= d) ? s[t - d] : 0;
        __syncthreads();
        s[t] += u;
        __syncthreads();
    }
    if (n < N_NODES) {
        int bo = boff[blockIdx.x];
        int excl = bo + s[t] - v;
        offs[n] = excl;
        cursor[n] = excl;
        if (n == N_NODES - 1) offs[N_NODES] = bo + s[t];
    }
}

__global__ __launch_bounds__(256) void place_kernel(const int* __restrict__ ei,
                                                    int* __restrict__ cursor,
                                                    int* __restrict__ csr) {
    int e = blockIdx.x * 256 + threadIdx.x;
    if (e < N_EDGES) {
        int d = ei[N_EDGES + e];
        int pos = atomicAdd(&cursor[d], 1);
        csr[pos] = ei[e];
    }
}

// ---------------- fused layer: out = relu(relu((h+Σ_nbr h)@W1+b1)@W2+b2) ----------------
// Block 256 = 4 waves, tile 64 rows. Gather phase: 16-lane group q=t&15 handles
// 8 channels [8q,8q+8) of rows {t>>4, +16, +32, +48}, accumulating in fp32 regs
// (8 outstanding uint4 loads), packing bf16 straight into sA — no agg buffer.
// MFMA phase: proven round-5 structure (a: A[m=lane&15][k=quad*8+j],
// b: B[k][n] from Wt[n][k], C/D: n=lane&15, m=quad*4+reg).
__global__ __launch_bounds__(256) void layer_kernel(const unsigned short* __restrict__ h,
                                                    const int* __restrict__ offs,
                                                    const int* __restrict__ csr,
                                                    const unsigned short* __restrict__ W1t,
                                                    const float* __restrict__ b1,
                                                    const unsigned short* __restrict__ W2t,
                                                    const float* __restrict__ b2,
                                                    unsigned short* __restrict__ out) {
    __shared__ unsigned short sA[64][136];  // row stride 272B = 17*16B
    __shared__ unsigned short sW[128][40];  // row stride 80B = 5*16B
    __shared__ float sb[128];
    const int t = threadIdx.x;
    const int w = t >> 6;
    const int l = t & 63;
    const int lm = l & 15;
    const int quad = l >> 4;
    const int row0 = blockIdx.x * 64;
    const int q = t & 15;

    // ---- gather phase: 4 rows per 16-lane group ----
    for (int rep = 0; rep < 4; ++rep) {
        int r = (t >> 4) + rep * 16;  // 0..63
        int node = row0 + r;
        float acc[8] = {0.f, 0.f, 0.f, 0.f, 0.f, 0.f, 0.f, 0.f};
        if (node < N_NODES) {
            addrow(acc, *(const uint4*)(h + (size_t)node * HID + q * 8));
            int e = offs[node], e1 = offs[node + 1];
            for (; e + 8 <= e1; e += 8) {
                int s0 = csr[e], s1 = csr[e + 1], s2 = csr[e + 2], s3 = csr[e + 3];
                int s4 = csr[e + 4], s5 = csr[e + 5], s6 = csr[e + 6], s7 = csr[e + 7];
                uint4 w0 = *(const uint4*)(h + (size_t)s0 * HID + q * 8);
                uint4 w1 = *(const uint4*)(h + (size_t)s1 * HID + q * 8);
                uint4 w2 = *(const uint4*)(h + (size_t)s2 * HID + q * 8);
                uint4 w3 = *(const uint4*)(h + (size_t)s3 * HID + q * 8);
                uint4 w4 = *(const uint4*)(h + (size_t)s4 * HID + q * 8);
                uint4 w5 = *(const uint4*)(h + (size_t)s5 * HID + q * 8);
                uint4 w6 = *(const uint4*)(h + (size_t)s6 * HID + q * 8);
                uint4 w7 = *(const uint4*)(h + (size_t)s7 * HID + q * 8);
                addrow(acc, w0); addrow(acc, w1); addrow(acc, w2); addrow(acc, w3);
                addrow(acc, w4); addrow(acc, w5); addrow(acc, w6); addrow(acc, w7);
            }
            for (; e + 4 <= e1; e += 4) {
                int s0 = csr[e], s1 = csr[e + 1], s2 = csr[e + 2], s3 = csr[e + 3];
                uint4 w0 = *(const uint4*)(h + (size_t)s0 * HID + q * 8);
                uint4 w1 = *(const uint4*)(h + (size_t)s1 * HID + q * 8);
                uint4 w2 = *(const uint4*)(h + (size_t)s2 * HID + q * 8);
                uint4 w3 = *(const uint4*)(h + (size_t)s3 * HID + q * 8);
                addrow(acc, w0); addrow(acc, w1); addrow(acc, w2); addrow(acc, w3);
            }
            for (; e < e1; ++e) {
                addrow(acc, *(const uint4*)(h + (size_t)csr[e] * HID + q * 8));
            }
        }
        uint4 o;
        o.x = pack2(acc[0], acc[1]);
        o.y = pack2(acc[2], acc[3]);
        o.z = pack2(acc[4], acc[5]);
        o.w = pack2(acc[6], acc[7]);
        *(uint4*)&sA[r][q * 8] = o;
    }

    const unsigned short* Wt[2] = {W1t, W2t};
    const float* bias[2] = {b1, b2};

    for (int p = 0; p < 2; ++p) {
        if (t < 128) sb[t] = bias[p][t];
        f32x4 acc[8];
#pragma unroll
        for (int nt = 0; nt < 8; ++nt) acc[nt] = (f32x4){0.f, 0.f, 0.f, 0.f};

        for (int kc = 0; kc < 4; ++kc) {
            __syncthreads();  // covers gather-phase sA writes on first pass
            for (int idx = t; idx < 512; idx += 256) {
                int n = idx >> 2, kq = idx & 3;
                *(uint4*)&sW[n][kq * 8] =
                    *(const uint4*)(Wt[p] + (size_t)n * HID + kc * 32 + kq * 8);
            }
            __syncthreads();
            bf16x8 a = *(const bf16x8*)&sA[w * 16 + lm][kc * 32 + quad * 8];
#pragma unroll
            for (int nt = 0; nt < 8; ++nt) {
                bf16x8 b = *(const bf16x8*)&sW[nt * 16 + lm][quad * 8];
                acc[nt] = __builtin_amdgcn_mfma_f32_16x16x32_bf16(a, b, acc[nt], 0, 0, 0);
            }
        }
        __syncthreads();  // all sA/sW reads done before overwrite
#pragma unroll
        for (int nt = 0; nt < 8; ++nt) {
            float bv = sb[nt * 16 + lm];
#pragma unroll
            for (int r = 0; r < 4; ++r) {
                int m = w * 16 + quad * 4 + r;
                float val = fmaxf(acc[nt][r] + bv, 0.f);
                sA[m][nt * 16 + lm] = f2bf(val);
            }
        }
        __syncthreads();
    }
    // store full tile
    for (int idx = t; idx < 1024; idx += 256) {
        int r = idx >> 4, c = idx & 15;
        int grow = row0 + r;
        if (grow < N_NODES)
            *(uint4*)(out + (size_t)grow * HID + c * 8) = *(const uint4*)&sA[r][c * 8];
    }
}

// ---------------- pool: g[batch[n]] += h[n] (batch sorted, bf16 in, fp32 out) ----------------
__global__ __launch_bounds__(128) void pool_kernel(const unsigned short* __restrict__ h,
                                                   const int* __restrict__ batch,
                                                   float* __restrict__ g) {
    const int CHUNK = 256;
    int c = threadIdx.x;
    int n0 = blockIdx.x * CHUNK;
    if (n0 >= N_NODES) return;
    int n1 = n0 + CHUNK;
    if (n1 > N_NODES) n1 = N_NODES;
    int cur = batch[n0];
    float acc = 0.f;
    for (int n = n0; n < n1; ++n) {
        int b = batch[n];
        if (b != cur) {
            atomicAdd(&g[(size_t)cur * HID + c], acc);
            acc = 0.f;
            cur = b;
        }
        acc += bf2f(h[(size_t)n * HID + c]);
    }
    atomicAdd(&g[(size_t)cur * HID + c], acc);
}

// ---------------- heads ----------------
__global__ __launch_bounds__(128) void head_kernel(const float* __restrict__ g,
                                                   const float* __restrict__ Wmu,
                                                   const float* __restrict__ bmu,
                                                   const float* __restrict__ Wlv,
                                                   const float* __restrict__ blv,
                                                   float* __restrict__ out) {
    __shared__ float sg[HID];
    int gi = blockIdx.x;
    sg[threadIdx.x] = g[(size_t)gi * HID + threadIdx.x];
    __syncthreads();
    int j = threadIdx.x & 63;
    bool is_lv = threadIdx.x >= 64;
    const float* W = is_lv ? Wlv : Wmu;
    float acc = is_lv ? blv[j] : bmu[j];
    for (int k = 0; k < HID; ++k) acc = fmaf(sg[k], W[k * LAT + j], acc);
    out[(is_lv ? (size_t)N_GRAPHS * LAT : 0) + (size_t)gi * LAT + j] = acc;
}

extern "C" void kernel_launch(void* const* d_in, const int* in_sizes, int n_in,
                              void* d_out, int out_size, void* d_ws, size_t ws_size,
                              hipStream_t stream) {
    const float* x     = (const float*)d_in[0];
    const int*   ei    = (const int*)d_in[1];
    const int*   batch = (const int*)d_in[2];
    const float* W1    = (const float*)d_in[3];
    const float* b1    = (const float*)d_in[4];
    const float* W2    = (const float*)d_in[5];
    const float* b2    = (const float*)d_in[6];
    const float* Wmu   = (const float*)d_in[7];
    const float* bmu   = (const float*)d_in[8];
    const float* Wlv   = (const float*)d_in[9];
    const float* blv   = (const float*)d_in[10];
    float* out = (float*)d_out;

    float* g = (float*)d_ws;
    unsigned short* xb   = (unsigned short*)(g + (size_t)N_GRAPHS * HID);
    unsigned short* hbufA = xb + (size_t)N_NODES * HID;
    unsigned short* hbufB = hbufA + (size_t)N_NODES * HID;
    unsigned short* Wt   = hbufB + (size_t)N_NODES * HID;
    int* deg    = (int*)(Wt + (size_t)6 * HID * HID);
    int* offs   = deg + N_NODES;
    int* cursor = offs + N_NODES + 1;
    int* bsum   = cursor + N_NODES;
    int* boff   = bsum + NB_SCAN;
    int* csr    = boff + NB_SCAN + 1;

    // ---- CSR build ----
    hipMemsetAsync(deg, 0, (size_t)N_NODES * sizeof(int), stream);
    count_kernel<<<(N_EDGES + 255) / 256, 256, 0, stream>>>(ei, deg);
    scanA_kernel<<<NB_SCAN, 256, 0, stream>>>(deg, bsum);
    scanB_kernel<<<1, 512, 0, stream>>>(bsum, boff);
    scanC_kernel<<<NB_SCAN, 256, 0, stream>>>(deg, boff, offs, cursor);
    place_kernel<<<(N_EDGES + 255) / 256, 256, 0, stream>>>(ei, cursor, csr);

    // ---- prep bf16 ----
    cvt_x_kernel<<<(N_NODES * HID / 4 + 255) / 256, 256, 0, stream>>>(x, xb,
                                                                      N_NODES * HID / 4);
    wt_kernel<<<6, 256, 0, stream>>>(W1, W2, Wt);

    const unsigned short* hcur = xb;
    unsigned short* hdst = hbufA;
    for (int i = 0; i < N_LAYERS; ++i) {
        layer_kernel<<<(N_NODES + 63) / 64, 256, 0, stream>>>(
            hcur, offs, csr,
            Wt + (size_t)(2 * i) * HID * HID, b1 + (size_t)i * HID,
            Wt + (size_t)(2 * i + 1) * HID * HID, b2 + (size_t)i * HID, hdst);
        hcur = hdst;
        hdst = (hdst == hbufA) ? hbufB : hbufA;
    }
    hipMemsetAsync(g, 0, (size_t)N_GRAPHS * HID * sizeof(float), stream);
    pool_kernel<<<(N_NODES + 255) / 256, 128, 0, stream>>>(hcur, batch, g);
    head_kernel<<<N_GRAPHS, 128, 0, stream>>>(g, Wmu, bmu, Wlv, blv, out);
}